// Round 8
// baseline (230.787 us; speedup 1.0000x reference)
//
#include <hip/hip_runtime.h>

#define HW 256
#define OW 254
#define RSTRIP 8             // output rows per wave strip; 32 strips/batch
#define NBLOCK 2048          // 256 batches * 8 blocks (4 waves each)
#define NGS (RSTRIP + 2)     // GS rows per strip
#define NPRED (NGS + 2)      // pred rows per strip
#define NOUT (256.0f * 254.0f * 254.0f)

// Load 8 pred values (cols c0-1 .. c0+6) with three aligned b128s, all
// lane-contiguous/coalesced. Slots consumed: 0..7 <-> cols c0-1..c0+6.
//  - left b128 at max(c0-4,0): only .w used (col c0-1); lane 0 garbage -> masked x=-1
//  - mid  b128 at c0: cols c0..c0+3
//  - right b128 at min(c0+4,HW-4): .x..z = cols c0+4..c0+6; lane 63 garbage -> masked
__device__ __forceinline__ void load_row8(const float* __restrict__ base, int row,
                                          int cA, int c0, int cB, float* p) {
    float4 vL = *(const float4*)&base[row * HW + cA];
    float4 v0 = *(const float4*)&base[row * HW + c0];
    float4 v1 = *(const float4*)&base[row * HW + cB];
    p[0] = vL.w;
    p[1] = v0.x; p[2] = v0.y; p[3] = v0.z; p[4] = v0.w;
    p[5] = v1.x; p[6] = v1.y; p[7] = v1.z;
}

// RR row slice cols c0..c0+5; row pre-clamped to [1,HW-2] (lane 63 spill stays
// in-plane; RR[0][0][0]==0 never reaches rcp).
__device__ __forceinline__ void load_rr6(const float* __restrict__ RRb, int row,
                                         int c0, float* rq) {
    float4 q0 = *(const float4*)&RRb[row * HW + c0];
    rq[0] = q0.x; rq[1] = q0.y; rq[2] = q0.z; rq[3] = q0.w;
    float2 q1 = *(const float2*)&RRb[row * HW + c0 + 4];
    rq[4] = q1.x; rq[5] = q1.y;
}

// rhs cols c0..c0+3 as two float2 (8B-aligned: row*254+c0 even).
// c2 = min(c0+2, OW-4): lane 63 slots 2,3 wrong-but-in-bounds, masked later.
__device__ __forceinline__ void load_rhs4v(const float* __restrict__ rhsb, int row,
                                           int c0, int c2, float* rh) {
    float2 a = *(const float2*)&rhsb[row * OW + c0];
    float2 b = *(const float2*)&rhsb[row * OW + c2];
    rh[0] = a.x; rh[1] = a.y; rh[2] = b.x; rh[3] = b.y;
}

__device__ __forceinline__ float uniformf(float x) {
    return __int_as_float(__builtin_amdgcn_readfirstlane(__float_as_int(x)));
}

__global__ __launch_bounds__(256, 1) void pde_loss_main(
    const float* __restrict__ pred, const float* __restrict__ rhs,
    const float* __restrict__ Lk,   const float* __restrict__ Dk,
    const float* __restrict__ RR,   const float* __restrict__ ZZ,
    float* __restrict__ partial)
{
    const int tid  = threadIdx.x;
    const int lane = tid & 63;
    const int wv   = tid >> 6;
    const int B    = blockIdx.x;
    // XCD-local mapping: batch = B % 256 -> all 8 blocks of a batch have the
    // same (B % 8) -> same XCD -> each XCD's L2 serves only 32 batches.
    const int b    = B & 255;
    const int strip= ((B >> 8) << 2) + wv;    // 0..31
    const int r0   = strip * RSTRIP;
    const int r1   = min(r0 + RSTRIP, OW);    // trims strip 31 (rows 248..253)

    const float* predb = pred + (size_t)b * (HW * HW);
    const float* RRb   = RR   + (size_t)b * (HW * HW);
    const float* ZZb   = ZZ   + (size_t)b * (HW * HW);
    const float* rhsb  = rhs  + (size_t)b * (OW * OW);

    // wave-uniform per-batch constants -> SGPRs
    float kl[9], kd[9];
    #pragma unroll
    for (int q = 0; q < 9; q++) {
        kl[q] = uniformf(Lk[b * 9 + q]);
        kd[q] = uniformf(Dk[b * 9 + q]);
    }
    float hr = RRb[1 * HW + 2] - RRb[1 * HW + 1];
    float hz = ZZb[2 * HW + 1] - ZZb[1 * HW + 1];
    float hr2 = hr * hr, hz2 = hz * hz;
    const float scale = uniformf((-2.0f * (hr2 + hz2)) / (hr2 * hz2));

    const int c0 = lane * 4;             // output col base (0..252)
    const int cA = max(c0 - 4, 0);
    const int cB = min(c0 + 4, HW - 4);
    const int c2 = min(c0 + 2, OW - 4);

    // ======== LOAD PHASE: whole strip, one burst (max MLP) ========
    float p[NPRED][8];
    #pragma unroll
    for (int s = 0; s < NPRED; ++s)
        load_row8(predb, min(max(r0 - 1 + s, 0), HW - 1), cA, c0, cB, p[s]);
    float rq[NGS][6];
    #pragma unroll
    for (int s = 0; s < NGS; ++s)
        load_rr6(RRb, min(max(r0 + s, 1), HW - 2), c0, rq[s]);
    float rh[RSTRIP][4];
    #pragma unroll
    for (int s = 0; s < RSTRIP; ++s)
        load_rhs4v(rhsb, min(r0 + s, OW - 1), c0, c2, rh[s]);

    // fence: keep the load burst ahead of the compute (R7-proven)
    __builtin_amdgcn_sched_barrier(0);

    // ======== COMPUTE PHASE: pure VALU, fully unrolled ========
    float P[4] = {0, 0, 0, 0};   // = H[i-1] + 2*H[i] for upcoming output row i
    float Q[4] = {0, 0, 0, 0};   // = H[i]
    float acc = 0.0f;

    #pragma unroll
    for (int s = 0; s < NGS; ++s) {
        const int g = r0 - 1 + s;            // GS row
        const bool rowok = (g >= 0) && (g < OW);

        float gs[6];
        #pragma unroll
        for (int u = 0; u < 6; ++u) {
            float sL = 0.0f, sD = 0.0f;
            #pragma unroll
            for (int kx = 0; kx < 3; ++kx) {
                sL = fmaf(p[s][u + kx],     kl[kx],     sL);
                sL = fmaf(p[s + 1][u + kx], kl[3 + kx], sL);
                sL = fmaf(p[s + 2][u + kx], kl[6 + kx], sL);
                sD = fmaf(p[s][u + kx],     kd[kx],     sD);
                sD = fmaf(p[s + 1][u + kx], kd[3 + kx], sD);
                sD = fmaf(p[s + 2][u + kx], kd[6 + kx], sD);
            }
            // GS = (Lpsi + convD/RR) * scale; rcp rel-err ~1e-7 << threshold
            float gval = scale * fmaf(sD, __builtin_amdgcn_rcpf(rq[s][u]), sL);
            int x = c0 - 1 + u;
            gs[u] = (rowok && x >= 0 && x < OW) ? gval : 0.0f;
        }

        // horizontal (1,2,1)
        float hb[4];
        #pragma unroll
        for (int t = 0; t < 4; ++t)
            hb[t] = gs[t] + 2.0f * gs[t + 1] + gs[t + 2];

        // output row i = g-1 completes: out = (H[i-1] + 2H[i] + H[i+1]) / 16
        const int i = g - 1;
        const bool iok = (s >= 2) && (i < r1);
        const float* rhrow = rh[(s >= 2) ? (s - 2) : 0];
        #pragma unroll
        for (int t = 0; t < 4; ++t) {
            float F = (P[t] + hb[t]) * (1.0f / 16.0f);
            float d = F - rhrow[t];
            acc += (iok && (c0 + t) < OW) ? d * d : 0.0f;
        }

        #pragma unroll
        for (int t = 0; t < 4; ++t) {
            P[t] = Q[t] + 2.0f * hb[t];
            Q[t] = hb[t];
        }
    }

    // wave (64) + block reduce (verbatim from passing R4..R7)
    #pragma unroll
    for (int off = 32; off > 0; off >>= 1)
        acc += __shfl_down(acc, off, 64);
    __shared__ float sw[4];
    if (lane == 0) sw[wv] = acc;
    __syncthreads();
    if (tid == 0)
        partial[blockIdx.x] = sw[0] + sw[1] + sw[2] + sw[3];
}

__global__ __launch_bounds__(256) void pde_loss_reduce(
    const float* __restrict__ partial, int n, float* __restrict__ out)
{
    float acc = 0.0f;
    for (int i = threadIdx.x; i < n; i += 256) acc += partial[i];
    #pragma unroll
    for (int off = 32; off > 0; off >>= 1)
        acc += __shfl_down(acc, off, 64);
    __shared__ float sw[4];
    if ((threadIdx.x & 63) == 0) sw[threadIdx.x >> 6] = acc;
    __syncthreads();
    if (threadIdx.x == 0)
        out[0] = (sw[0] + sw[1] + sw[2] + sw[3]) / NOUT;
}

extern "C" void kernel_launch(void* const* d_in, const int* in_sizes, int n_in,
                              void* d_out, int out_size, void* d_ws, size_t ws_size,
                              hipStream_t stream) {
    const float* pred = (const float*)d_in[0];
    const float* rhs  = (const float*)d_in[1];
    const float* Lk   = (const float*)d_in[2];
    const float* Dk   = (const float*)d_in[3];
    const float* RR   = (const float*)d_in[4];
    const float* ZZ   = (const float*)d_in[5];
    float* out = (float*)d_out;
    float* partial = (float*)d_ws;   // NBLOCK floats = 8 KiB

    pde_loss_main<<<NBLOCK, 256, 0, stream>>>(pred, rhs, Lk, Dk, RR, ZZ, partial);
    pde_loss_reduce<<<1, 256, 0, stream>>>(partial, NBLOCK, out);
}

// Round 9
// 226.913 us; speedup vs baseline: 1.0171x; 1.0171x over previous
//
#include <hip/hip_runtime.h>

#define HW 256
#define OW 254
#define RSTRIP 6             // output rows per wave strip
#define NSTRIPS 43           // ceil(254/6); strip 42 covers rows 252..253
#define NWAVES (256 * NSTRIPS)
#define NBLOCK (NWAVES / 4)  // 2752
#define NGS (RSTRIP + 2)     // GS rows per strip
#define NPRED (NGS + 2)      // pred rows per strip
#define NOUT (256.0f * 254.0f * 254.0f)

// rhs cols c0..c0+3 as two float2 (8B-aligned: row*254+c0 even).
// c2 = min(c0+2, OW-4): lane 63 slots 2,3 wrong-but-in-bounds, masked later.
__device__ __forceinline__ void load_rhs4v(const float* __restrict__ rhsb, int row,
                                           int c0, int c2, float* rh) {
    float2 a = *(const float2*)&rhsb[row * OW + c0];
    float2 b = *(const float2*)&rhsb[row * OW + c2];
    rh[0] = a.x; rh[1] = a.y; rh[2] = b.x; rh[3] = b.y;
}

__device__ __forceinline__ float uniformf(float x) {
    return __int_as_float(__builtin_amdgcn_readfirstlane(__float_as_int(x)));
}

__global__ __launch_bounds__(256, 1) void pde_loss_main(
    const float* __restrict__ pred, const float* __restrict__ rhs,
    const float* __restrict__ Lk,   const float* __restrict__ Dk,
    const float* __restrict__ RR,   const float* __restrict__ ZZ,
    float* __restrict__ partial)
{
    const int tid  = threadIdx.x;
    const int lane = tid & 63;
    const int wv   = tid >> 6;
    const int gw   = blockIdx.x * 4 + wv;     // global wave id (< NWAVES)
    const int b    = gw / NSTRIPS;            // magic-mul division
    const int strip= gw - b * NSTRIPS;
    const int r0   = strip * RSTRIP;
    const int r1   = min(r0 + RSTRIP, OW);

    const float* predb = pred + (size_t)b * (HW * HW);
    const float* RRb   = RR   + (size_t)b * (HW * HW);
    const float* ZZb   = ZZ   + (size_t)b * (HW * HW);
    const float* rhsb  = rhs  + (size_t)b * (OW * OW);

    // wave-uniform per-batch constants -> SGPRs
    float kl[9], kd[9];
    #pragma unroll
    for (int q = 0; q < 9; q++) {
        kl[q] = uniformf(Lk[b * 9 + q]);
        kd[q] = uniformf(Dk[b * 9 + q]);
    }
    float hr = RRb[1 * HW + 2] - RRb[1 * HW + 1];
    float hz = ZZb[2 * HW + 1] - ZZb[1 * HW + 1];
    float hr2 = hr * hr, hz2 = hz * hz;
    const float scale = uniformf((-2.0f * (hr2 + hz2)) / (hr2 * hz2));

    const int c0 = lane * 4;             // output col base (0..252)

    // ======== LOAD PHASE: ONE aligned b128 per row per lane (max MLP, min instrs) ========
    float4 pm[NPRED];                    // pred row mids: cols c0..c0+3
    #pragma unroll
    for (int s = 0; s < NPRED; ++s)
        pm[s] = *(const float4*)&predb[min(max(r0 - 1 + s, 0), HW - 1) * HW + c0];
    float4 qm[NGS];                      // RR row mids: cols c0..c0+3, row in [1,254]
    #pragma unroll
    for (int s = 0; s < NGS; ++s)
        qm[s] = *(const float4*)&RRb[min(max(r0 + s, 1), HW - 2) * HW + c0];
    float rh[RSTRIP][4];
    #pragma unroll
    for (int s = 0; s < RSTRIP; ++s)
        load_rhs4v(rhsb, min(r0 + s, OW - 1), c0, min(c0 + 2, OW - 4), rh[s]);

    // fence: keep the load burst ahead of everything else (R7-proven)
    __builtin_amdgcn_sched_barrier(0);

    // ======== HALO MATERIALIZATION: lane+-1 shuffles, garbage only feeds masked pts ====
    // p[s][t] <-> pred col c0-1+t. slot0: lane0 garbage -> only GS x=-1 (masked).
    // slots 5,6,7: lane63 garbage -> only GS x>=254 (masked).
    float p[NPRED][8];
    #pragma unroll
    for (int s = 0; s < NPRED; ++s) {
        p[s][0] = __shfl_up(pm[s].w, 1);
        p[s][1] = pm[s].x; p[s][2] = pm[s].y; p[s][3] = pm[s].z; p[s][4] = pm[s].w;
        p[s][5] = __shfl_down(pm[s].x, 1);
        p[s][6] = __shfl_down(pm[s].y, 1);
        p[s][7] = __shfl_down(pm[s].z, 1);
    }
    // rq[s][u] = RR[row][c0+u], u=0..5. u=4,5 from lane+1 (lane63 garbage ->
    // feeds u=4,5 whose x=c0+3+.. >= 254 for lane63 -> masked; select (not
    // arithmetic) masking keeps any inf/NaN from reaching acc.
    float rq[NGS][6];
    #pragma unroll
    for (int s = 0; s < NGS; ++s) {
        rq[s][0] = qm[s].x; rq[s][1] = qm[s].y; rq[s][2] = qm[s].z; rq[s][3] = qm[s].w;
        rq[s][4] = __shfl_down(qm[s].x, 1);
        rq[s][5] = __shfl_down(qm[s].y, 1);
    }

    // ======== COMPUTE PHASE: pure VALU, fully unrolled ========
    float P[4] = {0, 0, 0, 0};   // = H[i-1] + 2*H[i] for upcoming output row i
    float Q[4] = {0, 0, 0, 0};   // = H[i]
    float acc = 0.0f;

    #pragma unroll
    for (int s = 0; s < NGS; ++s) {
        const int g = r0 - 1 + s;            // GS row
        const bool rowok = (g >= 0) && (g < OW);

        float gs[6];
        #pragma unroll
        for (int u = 0; u < 6; ++u) {
            float sL = 0.0f, sD = 0.0f;
            #pragma unroll
            for (int kx = 0; kx < 3; ++kx) {
                sL = fmaf(p[s][u + kx],     kl[kx],     sL);
                sL = fmaf(p[s + 1][u + kx], kl[3 + kx], sL);
                sL = fmaf(p[s + 2][u + kx], kl[6 + kx], sL);
                sD = fmaf(p[s][u + kx],     kd[kx],     sD);
                sD = fmaf(p[s + 1][u + kx], kd[3 + kx], sD);
                sD = fmaf(p[s + 2][u + kx], kd[6 + kx], sD);
            }
            // GS = (Lpsi + convD/RR) * scale; rcp rel-err ~1e-7 << threshold
            float gval = scale * fmaf(sD, __builtin_amdgcn_rcpf(rq[s][u]), sL);
            int x = c0 - 1 + u;
            gs[u] = (rowok && x >= 0 && x < OW) ? gval : 0.0f;
        }

        // horizontal (1,2,1)
        float hb[4];
        #pragma unroll
        for (int t = 0; t < 4; ++t)
            hb[t] = gs[t] + 2.0f * gs[t + 1] + gs[t + 2];

        // output row i = g-1 completes: out = (H[i-1] + 2H[i] + H[i+1]) / 16
        const int i = g - 1;
        const bool iok = (s >= 2) && (i < r1);
        const float* rhrow = rh[(s >= 2) ? (s - 2) : 0];
        #pragma unroll
        for (int t = 0; t < 4; ++t) {
            float F = (P[t] + hb[t]) * (1.0f / 16.0f);
            float d = F - rhrow[t];
            acc += (iok && (c0 + t) < OW) ? d * d : 0.0f;
        }

        #pragma unroll
        for (int t = 0; t < 4; ++t) {
            P[t] = Q[t] + 2.0f * hb[t];
            Q[t] = hb[t];
        }
    }

    // wave (64) + block reduce (verbatim from passing R4..R8)
    #pragma unroll
    for (int off = 32; off > 0; off >>= 1)
        acc += __shfl_down(acc, off, 64);
    __shared__ float sw[4];
    if (lane == 0) sw[wv] = acc;
    __syncthreads();
    if (tid == 0)
        partial[blockIdx.x] = sw[0] + sw[1] + sw[2] + sw[3];
}

__global__ __launch_bounds__(256) void pde_loss_reduce(
    const float* __restrict__ partial, int n, float* __restrict__ out)
{
    float acc = 0.0f;
    for (int i = threadIdx.x; i < n; i += 256) acc += partial[i];
    #pragma unroll
    for (int off = 32; off > 0; off >>= 1)
        acc += __shfl_down(acc, off, 64);
    __shared__ float sw[4];
    if ((threadIdx.x & 63) == 0) sw[threadIdx.x >> 6] = acc;
    __syncthreads();
    if (threadIdx.x == 0)
        out[0] = (sw[0] + sw[1] + sw[2] + sw[3]) / NOUT;
}

extern "C" void kernel_launch(void* const* d_in, const int* in_sizes, int n_in,
                              void* d_out, int out_size, void* d_ws, size_t ws_size,
                              hipStream_t stream) {
    const float* pred = (const float*)d_in[0];
    const float* rhs  = (const float*)d_in[1];
    const float* Lk   = (const float*)d_in[2];
    const float* Dk   = (const float*)d_in[3];
    const float* RR   = (const float*)d_in[4];
    const float* ZZ   = (const float*)d_in[5];
    float* out = (float*)d_out;
    float* partial = (float*)d_ws;   // NBLOCK floats = 11 KiB

    pde_loss_main<<<NBLOCK, 256, 0, stream>>>(pred, rhs, Lk, Dk, RR, ZZ, partial);
    pde_loss_reduce<<<1, 256, 0, stream>>>(partial, NBLOCK, out);
}